// Round 16
// baseline (1937.808 us; speedup 1.0000x reference)
//
#include <hip/hip_runtime.h>
#include <float.h>
#include <math.h>

#define BB   4
#define NPTS 8192
#define MS   1024
#define DIM  768
#define NH   12
#define DHD  64
#define KNN  8
#define BMD  (BB*MS*DIM)

typedef float v2f __attribute__((ext_vector_type(2)));

static __device__ __forceinline__ float sqdist3(float ax, float ay, float az,
                                                float bx, float by, float bz) {
  float dx = __fsub_rn(ax, bx);
  float dy = __fsub_rn(ay, by);
  float dz = __fsub_rn(az, bz);
  // match XLA: elementwise square (mul), then sequential sum — no fma contraction
  return __fadd_rn(__fadd_rn(__fmul_rn(dx, dx), __fmul_rn(dy, dy)), __fmul_rn(dz, dz));
}

// Forced packed-f32 ops (2 lanes' points per instruction). IEEE: a+(-b) == a-b
// bit-exactly, and v_pk_{add,mul}_f32 round identically to the scalar ops, so
// FPS selection stays bit-identical to XLA's mul-then-add sequence.
static __device__ __forceinline__ v2f pk_sub(v2f a, v2f b) {
  v2f d;
  asm("v_pk_add_f32 %0, %1, %2 neg_lo:[0,1] neg_hi:[0,1]" : "=v"(d) : "v"(a), "v"(b));
  return d;
}
static __device__ __forceinline__ v2f pk_mul(v2f a, v2f b) {
  v2f d;
  asm("v_pk_mul_f32 %0, %1, %2" : "=v"(d) : "v"(a), "v"(b));
  return d;
}
static __device__ __forceinline__ v2f pk_add(v2f a, v2f b) {
  v2f d;
  asm("v_pk_add_f32 %0, %1, %2" : "=v"(d) : "v"(a), "v"(b));
  return d;
}

#define DPP_STAGE(key, ctrl)                                                   \
  {                                                                            \
    unsigned hi_ = (unsigned)((key) >> 32), lo_ = (unsigned)(key);             \
    unsigned nhi_ = (unsigned)__builtin_amdgcn_update_dpp(                     \
        (int)hi_, (int)hi_, (ctrl), 0xf, 0xf, false);                          \
    unsigned nlo_ = (unsigned)__builtin_amdgcn_update_dpp(                     \
        (int)lo_, (int)lo_, (ctrl), 0xf, 0xf, false);                          \
    unsigned long long nk_ = ((unsigned long long)nhi_ << 32) | nlo_;          \
    if (nk_ > (key)) (key) = nk_;                                              \
  }

// ---------------------------------------------------------------------------
// 1) FPS v6: one block/batch, 1024 threads, 8 pts/thread as 4x float2.
//    R15 counters: serial reduce overhead + issue not overlapped at 2
//    waves/SIMD. v6: (a) 4 waves/SIMD so update-issue hides the serial DPP/
//    barrier chain; (b) hierarchical reduce — per-wave 6-stage DPP, then
//    wave 0 ONLY does a lane-parallel 4-stage DPP tree over the 16 wave
//    winners (no redundant all-wave tree), publishes winner coords via LDS;
//    (c) inline-asm v_pk ops (2 pts/inst) for the distance update.
//    Key = (distbits<<32 | ~idx): u64 max => max dist, tie -> lowest idx
//    (jnp.argmax). 2 barriers/iter; single-buffered LDS is race-free.
// ---------------------------------------------------------------------------
__global__ __launch_bounds__(1024, 1) void fps_kernel(const float* __restrict__ points,
                                                      float* __restrict__ sampled) {
#pragma clang fp contract(off)
  const int b = blockIdx.x;
  const float* pts = points + (size_t)b * NPTS * 3;
  float* smp = sampled + (size_t)b * MS * 3;
  const int tid = threadIdx.x;
  const int lane = tid & 63, wid = tid >> 6;

  __shared__ float4 cxyz[NPTS];                     // 128 KB coord cache
  __shared__ unsigned long long red[16];
  __shared__ float4 fin;

  v2f px[4], py[4], pz[4], md[4];
  const float qx0 = pts[0], qy0 = pts[1], qz0 = pts[2];

  float bv = -INFINITY;
  int bidx = 0;
#pragma unroll
  for (int j = 0; j < 4; ++j) {
    int i0 = 2 * tid + j * 2048;                    // pair (i0, i0+1); even=.x
    float x0 = pts[i0 * 3 + 0], y0 = pts[i0 * 3 + 1], z0 = pts[i0 * 3 + 2];
    float x1 = pts[i0 * 3 + 3], y1 = pts[i0 * 3 + 4], z1 = pts[i0 * 3 + 5];
    px[j] = (v2f){x0, x1}; py[j] = (v2f){y0, y1}; pz[j] = (v2f){z0, z1};
    cxyz[i0]     = make_float4(x0, y0, z0, 0.f);
    cxyz[i0 + 1] = make_float4(x1, y1, z1, 0.f);
    v2f dx = pk_sub(px[j], (v2f){qx0, qx0});
    v2f dy = pk_sub(py[j], (v2f){qy0, qy0});
    v2f dz = pk_sub(pz[j], (v2f){qz0, qz0});
    v2f d  = pk_add(pk_add(pk_mul(dx, dx), pk_mul(dy, dy)), pk_mul(dz, dz));
    md[j] = d;
    if (d.x > bv) { bv = d.x; bidx = i0; }          // .x first => lower idx on tie
    if (d.y > bv) { bv = d.y; bidx = i0 + 1; }
  }
  if (tid == 0) { smp[0] = qx0; smp[1] = qy0; smp[2] = qz0; }
  __syncthreads();

  for (int s = 1; s < MS; ++s) {
    unsigned long long key =
        ((unsigned long long)__float_as_uint(bv) << 32) |
        (unsigned)(~(unsigned)bidx);

    // per-wave 6-stage DPP merge -> lane63 = wave winner
    DPP_STAGE(key, 0xB1);   // quad_perm [1,0,3,2]
    DPP_STAGE(key, 0x4E);   // quad_perm [2,3,0,1]
    DPP_STAGE(key, 0x141);  // row_half_mirror
    DPP_STAGE(key, 0x140);  // row_mirror
    DPP_STAGE(key, 0x142);  // row_bcast15
    DPP_STAGE(key, 0x143);  // row_bcast31

    if (lane == 63) red[wid] = key;
    __syncthreads();

    // wave 0 only: lane-parallel tree over the 16 wave winners.
    // lanes load red[lane&15] (rows replicate) -> 4 row-local DPP stages
    // combine all 16 -> every lane holds the winner; lane 0 publishes.
    if (wid == 0) {
      unsigned long long k = red[lane & 15];
      DPP_STAGE(k, 0xB1);
      DPP_STAGE(k, 0x4E);
      DPP_STAGE(k, 0x141);
      DPP_STAGE(k, 0x140);
      if (lane == 0) {
        const unsigned widx = ~(unsigned)(k & 0xffffffffull);
        float4 wc = cxyz[widx];
        fin = wc;
        smp[s * 3 + 0] = wc.x; smp[s * 3 + 1] = wc.y; smp[s * 3 + 2] = wc.z;
      }
    }
    __syncthreads();

    const float4 wc = fin;                          // broadcast b128 read
    const v2f wx = (v2f){wc.x, wc.x}, wy = (v2f){wc.y, wc.y}, wz = (v2f){wc.z, wc.z};

    bv = -INFINITY; bidx = 0;
#pragma unroll
    for (int j = 0; j < 4; ++j) {
      int i0 = 2 * tid + j * 2048;
      v2f dx = pk_sub(px[j], wx), dy = pk_sub(py[j], wy), dz = pk_sub(pz[j], wz);
      v2f d  = pk_add(pk_add(pk_mul(dx, dx), pk_mul(dy, dy)), pk_mul(dz, dz));
      v2f nm = __builtin_elementwise_min(md[j], d);
      md[j] = nm;
      if (nm.x > bv) { bv = nm.x; bidx = i0; }
      if (nm.y > bv) { bv = nm.y; bidx = i0 + 1; }
    }
  }
}

// ---------------------------------------------------------------------------
// 2) Point embedding: feats = sampled @ W_embed + b_embed    [B*M, 768]
// ---------------------------------------------------------------------------
__global__ void embed_kernel(const float* __restrict__ sampled,
                             const float* __restrict__ W,
                             const float* __restrict__ bias,
                             float* __restrict__ out) {
  int idx = blockIdx.x * blockDim.x + threadIdx.x;
  if (idx >= BMD) return;
  int d = idx % DIM;
  int bm = idx / DIM;
  float x = sampled[bm * 3 + 0], y = sampled[bm * 3 + 1], z = sampled[bm * 3 + 2];
  out[idx] = fmaf(z, W[2 * DIM + d], fmaf(y, W[DIM + d], fmaf(x, W[d], bias[d])));
}

// ---------------------------------------------------------------------------
// 3) kNN (k=8, incl. self) + edge = feat - mean(neighbor feats)
// ---------------------------------------------------------------------------
__global__ __launch_bounds__(256) void knn_edge_kernel(const float* __restrict__ sampled,
                                                       const float* __restrict__ feats,
                                                       float* __restrict__ edge) {
  const int bm = blockIdx.x;
  const int b = bm >> 10, m = bm & 1023;
  const float* sp = sampled + (size_t)b * MS * 3;
  const int t = threadIdx.x, lane = t & 63, wid = t >> 6;

  __shared__ float dist[MS];
  __shared__ float redv[4];
  __shared__ int   redi[4];
  __shared__ int   win[KNN];

  const float qx = sp[m * 3 + 0], qy = sp[m * 3 + 1], qz = sp[m * 3 + 2];
#pragma unroll
  for (int j = 0; j < 4; ++j) {
    int i = t + j * 256;
    dist[i] = sqdist3(sp[i * 3 + 0], sp[i * 3 + 1], sp[i * 3 + 2], qx, qy, qz);
  }
  __syncthreads();

  for (int it = 0; it < KNN; ++it) {
    float bv = dist[t]; int bi = t;
#pragma unroll
    for (int j = 1; j < 4; ++j) {
      int i = t + j * 256;
      float v = dist[i];
      if (v < bv || (v == bv && i < bi)) { bv = v; bi = i; }
    }
#pragma unroll
    for (int off = 32; off >= 1; off >>= 1) {
      float ov = __shfl_xor(bv, off);
      int   oi = __shfl_xor(bi, off);
      if (ov < bv || (ov == bv && oi < bi)) { bv = ov; bi = oi; }
    }
    if (lane == 0) { redv[wid] = bv; redi[wid] = bi; }
    __syncthreads();
    if (t == 0) {
      float wv = redv[0]; int wi = redi[0];
#pragma unroll
      for (int w = 1; w < 4; ++w) {
        float ov = redv[w]; int oi = redi[w];
        if (ov < wv || (ov == wv && oi < wi)) { wv = ov; wi = oi; }
      }
      win[it] = wi;
      dist[wi] = FLT_MAX;
    }
    __syncthreads();
  }

  const float* fb = feats + (size_t)b * MS * DIM;
  float* eb = edge + (size_t)b * MS * DIM;
  for (int d = t; d < DIM; d += 256) {
    float acc = 0.f;
#pragma unroll
    for (int i = 0; i < KNN; ++i) acc += fb[(size_t)win[i] * DIM + d];
    eb[(size_t)m * DIM + d] = fb[(size_t)m * DIM + d] - acc * 0.125f;
  }
}

// ---------------------------------------------------------------------------
// 4) fp32 tiled GEMM v2: C[4096,768] = A @ W + bias. 128x64 tile, 8x4 micro.
//    MODE 1: also += sampled@Ws + bs (final epilogue)
// ---------------------------------------------------------------------------
template <int MODE>
__global__ __launch_bounds__(256) void gemm_kernel(const float* __restrict__ A,
                                                   const float* __restrict__ W,
                                                   const float* __restrict__ bias,
                                                   float* __restrict__ C,
                                                   const float* __restrict__ sampled,
                                                   const float* __restrict__ Ws,
                                                   const float* __restrict__ bs) {
  __shared__ float As[16][132];   // [k][m], padded
  __shared__ float Bs[16][68];    // [k][n], padded

  const int t = threadIdx.x;
  const int tx = t & 15, ty = t >> 4;      // tx: n/4, ty: m/8
  const int rowBase = blockIdx.x * 128;
  const int nBase = blockIdx.y * 64;

  float c[8][4] = {};

  const int ar = t >> 1, ac8 = (t & 1) * 8;   // A: 128 rows x 16 k, 2 float4/thread
  const int br = t >> 4, bc4 = (t & 15) * 4;  // B: 16 k x 64 n, 1 float4/thread

  for (int k0 = 0; k0 < DIM; k0 += 16) {
    float4 a0 = *(const float4*)&A[(size_t)(rowBase + ar) * DIM + k0 + ac8];
    float4 a1 = *(const float4*)&A[(size_t)(rowBase + ar) * DIM + k0 + ac8 + 4];
    As[ac8 + 0][ar] = a0.x; As[ac8 + 1][ar] = a0.y;
    As[ac8 + 2][ar] = a0.z; As[ac8 + 3][ar] = a0.w;
    As[ac8 + 4][ar] = a1.x; As[ac8 + 5][ar] = a1.y;
    As[ac8 + 6][ar] = a1.z; As[ac8 + 7][ar] = a1.w;
    float4 wv = *(const float4*)&W[(size_t)(k0 + br) * DIM + nBase + bc4];
    *(float4*)&Bs[br][bc4] = wv;
    __syncthreads();
#pragma unroll
    for (int k = 0; k < 16; ++k) {
      float av[8], bv[4];
      *(float4*)&av[0] = *(const float4*)&As[k][ty * 8];
      *(float4*)&av[4] = *(const float4*)&As[k][ty * 8 + 4];
      *(float4*)bv = *(const float4*)&Bs[k][tx * 4];
#pragma unroll
      for (int i = 0; i < 8; ++i)
#pragma unroll
        for (int j = 0; j < 4; ++j)
          c[i][j] = fmaf(av[i], bv[j], c[i][j]);
    }
    __syncthreads();
  }

#pragma unroll
  for (int i = 0; i < 8; ++i) {
    int row = rowBase + ty * 8 + i;
#pragma unroll
    for (int j = 0; j < 4; ++j) {
      int n = nBase + tx * 4 + j;
      float v = c[i][j] + bias[n];
      if (MODE == 1) {
        const float* sp = sampled + (size_t)row * 3;
        float spt = fmaf(sp[2], Ws[2 * DIM + n], fmaf(sp[1], Ws[DIM + n], fmaf(sp[0], Ws[n], bs[n])));
        v += spt;
      }
      C[(size_t)row * DIM + n] = v;
    }
  }
}

// ---------------------------------------------------------------------------
// 5) Attention v2 (unchanged): 64-row tile, 4 waves, 4x4 register micro-tiles,
//    XOR-swizzled LDS, per-wave P buffer, 2 barriers/tile.
// ---------------------------------------------------------------------------
static __device__ __forceinline__ int lidx(int r, int c) {
  return r * 64 + (c ^ ((r & 7) << 2));
}

__global__ __launch_bounds__(256) void attn_kernel(const float* __restrict__ Q,
                                                   const float* __restrict__ K,
                                                   const float* __restrict__ V,
                                                   float* __restrict__ O) {
  const int nrt = MS / 64;                    // 16 row-tiles
  const int blk = blockIdx.x;                 // B*NH*nrt
  const int bh = blk / nrt, rt = blk % nrt;
  const int b = bh / NH, h = bh % NH;
  const int t = threadIdx.x, lane = t & 63, w = t >> 6;
  const int rg = lane >> 4, kg = lane & 15;

  __shared__ float Qs[64 * 64];
  __shared__ float Ks[64 * 64];
  __shared__ float Vs[64 * 64];
  __shared__ float Ps[4 * 16 * 64];           // per-wave private P

  const size_t base = (size_t)(b * MS) * DIM + (size_t)h * DHD;

#pragma unroll
  for (int i = 0; i < 4; ++i) {
    int f = t + i * 256;
    int r = f >> 4, c4 = (f & 15) * 4;
    *(float4*)&Qs[lidx(r, c4)] = *(const float4*)&Q[base + (size_t)(rt * 64 + r) * DIM + c4];
  }

  float m[4], l[4], o[4][4];
#pragma unroll
  for (int i = 0; i < 4; ++i) {
    m[i] = -INFINITY; l[i] = 0.f;
#pragma unroll
    for (int j = 0; j < 4; ++j) o[i][j] = 0.f;
  }

  const int lrow = w * 16 + rg * 4;
  float* Pw = &Ps[w * 16 * 64];

  for (int kt = 0; kt < nrt; ++kt) {
#pragma unroll
    for (int i = 0; i < 4; ++i) {
      int f = t + i * 256;
      int r = f >> 4, c4 = (f & 15) * 4;
      size_t g = base + (size_t)(kt * 64 + r) * DIM + c4;
      *(float4*)&Ks[lidx(r, c4)] = *(const float4*)&K[g];
      *(float4*)&Vs[lidx(r, c4)] = *(const float4*)&V[g];
    }
    __syncthreads();

    float s[4][4] = {};
#pragma unroll 8
    for (int d = 0; d < 64; ++d) {
      float a[4], bb[4];
#pragma unroll
      for (int i = 0; i < 4; ++i) a[i] = Qs[lidx(lrow + i, d)];
#pragma unroll
      for (int j = 0; j < 4; ++j) bb[j] = Ks[lidx(kg + 16 * j, d)];
#pragma unroll
      for (int i = 0; i < 4; ++i)
#pragma unroll
        for (int j = 0; j < 4; ++j) s[i][j] = fmaf(a[i], bb[j], s[i][j]);
    }

#pragma unroll
    for (int i = 0; i < 4; ++i) {
#pragma unroll
      for (int j = 0; j < 4; ++j) s[i][j] *= 0.125f;   // 1/sqrt(64)
      float mt = fmaxf(fmaxf(s[i][0], s[i][1]), fmaxf(s[i][2], s[i][3]));
#pragma unroll
      for (int off = 1; off < 16; off <<= 1) mt = fmaxf(mt, __shfl_xor(mt, off));
      float mn = fmaxf(m[i], mt);
      float corr = expf(m[i] - mn);
      float ps = 0.f;
#pragma unroll
      for (int j = 0; j < 4; ++j) { s[i][j] = expf(s[i][j] - mn); ps += s[i][j]; }
#pragma unroll
      for (int off = 1; off < 16; off <<= 1) ps += __shfl_xor(ps, off);
      l[i] = l[i] * corr + ps;
      m[i] = mn;
#pragma unroll
      for (int j = 0; j < 4; ++j) o[i][j] *= corr;
#pragma unroll
      for (int j = 0; j < 4; ++j) Pw[lidx(rg * 4 + i, kg + 16 * j)] = s[i][j];
    }

#pragma unroll 8
    for (int k = 0; k < 64; ++k) {
      float a[4], bb[4];
#pragma unroll
      for (int i = 0; i < 4; ++i) a[i] = Pw[lidx(rg * 4 + i, k)];
#pragma unroll
      for (int j = 0; j < 4; ++j) bb[j] = Vs[lidx(k, kg + 16 * j)];
#pragma unroll
      for (int i = 0; i < 4; ++i)
#pragma unroll
        for (int j = 0; j < 4; ++j) o[i][j] = fmaf(a[i], bb[j], o[i][j]);
    }
    __syncthreads();
  }

#pragma unroll
  for (int i = 0; i < 4; ++i) {
    int row = rt * 64 + lrow + i;
#pragma unroll
    for (int j = 0; j < 4; ++j)
      O[base + (size_t)row * DIM + kg + 16 * j] = o[i][j] / l[i];
  }
}

// ---------------------------------------------------------------------------
extern "C" void kernel_launch(void* const* d_in, const int* in_sizes, int n_in,
                              void* d_out, int out_size, void* d_ws, size_t ws_size,
                              hipStream_t stream) {
  const float* points  = (const float*)d_in[0];
  const float* W_embed = (const float*)d_in[1];
  const float* b_embed = (const float*)d_in[2];
  const float* Wq = (const float*)d_in[3];
  const float* bq = (const float*)d_in[4];
  const float* Wk = (const float*)d_in[5];
  const float* bk = (const float*)d_in[6];
  const float* Wv = (const float*)d_in[7];
  const float* bv = (const float*)d_in[8];
  const float* Wo = (const float*)d_in[9];
  const float* bo = (const float*)d_in[10];
  const float* Ws = (const float*)d_in[11];
  const float* bs = (const float*)d_in[12];

  float* ws = (float*)d_ws;
  float* sampled = ws;                 // B*M*3
  float* feats   = ws + 16384;
  float* edge    = feats + BMD;
  float* qb      = edge + BMD;
  float* kb      = qb + BMD;
  float* vb      = kb + BMD;
  float* ao      = vb + BMD;

  fps_kernel<<<BB, 1024, 0, stream>>>(points, sampled);
  embed_kernel<<<(BMD + 255) / 256, 256, 0, stream>>>(sampled, W_embed, b_embed, feats);
  knn_edge_kernel<<<BB * MS, 256, 0, stream>>>(sampled, feats, edge);

  dim3 ggrid(4096 / 128, DIM / 64);
  gemm_kernel<0><<<ggrid, 256, 0, stream>>>(edge, Wq, bq, qb, nullptr, nullptr, nullptr);
  gemm_kernel<0><<<ggrid, 256, 0, stream>>>(edge, Wk, bk, kb, nullptr, nullptr, nullptr);
  gemm_kernel<0><<<ggrid, 256, 0, stream>>>(edge, Wv, bv, vb, nullptr, nullptr, nullptr);

  attn_kernel<<<BB * NH * (MS / 64), 256, 0, stream>>>(qb, kb, vb, ao);

  gemm_kernel<1><<<ggrid, 256, 0, stream>>>(ao, Wo, bo, (float*)d_out, sampled, Ws, bs);
}